// Round 1
// baseline (792.576 us; speedup 1.0000x reference)
//
#include <hip/hip_runtime.h>
#include <hip/hip_bf16.h>
#include <stdint.h>

// Problem dims (fixed by the reference)
// B=256, T=512, I=512, L=128, D=4, O=2
// M = B*T = 131072 rows, N = L*D = 512 cols, K = I = 512

typedef __bf16 bf16x8 __attribute__((ext_vector_type(8)));
typedef float f32x4_t __attribute__((ext_vector_type(4)));

__device__ inline unsigned short f2bf(float f) {
    union { float f; unsigned u; } v; v.f = f;
    unsigned r = v.u + 0x7fffu + ((v.u >> 16) & 1u);   // round-to-nearest-even
    return (unsigned short)(r >> 16);
}

// ---------------------------------------------------------------------------
// Phase 1: merged_in[m][l] = sum_d gate[l*4+d] * relu( sum_k x[m][k]*W_in[l*4+d][k] )
// bf16 MFMA GEMM, 128x128 tile, BK=32, 256 threads (4 waves, 2x2 wave grid,
// wave tile 64x64 = 4x4 fragments of 16x16x32).
// Both A (x) and B (W_in) are staged f32->bf16 into LDS each K-step.
// ---------------------------------------------------------------------------
__global__ __launch_bounds__(256, 2)
void gemm_in_kernel(const float* __restrict__ x, const float* __restrict__ W_in,
                    const float* __restrict__ W_gate, float* __restrict__ merged)
{
    __shared__ unsigned short As[128 * 32];   // 8 KiB
    __shared__ unsigned short Bs[128 * 32];   // 8 KiB

    const int tid = threadIdx.x;
    const int m0 = blockIdx.y * 128;
    const int n0 = blockIdx.x * 128;
    const int lane = tid & 63;
    const int wid  = tid >> 6;
    const int wr = wid >> 1, wc = wid & 1;    // 2x2 wave grid
    const int fr = lane & 15, fq = lane >> 4; // fragment row / k-quarter

    f32x4_t acc[4][4];
    #pragma unroll
    for (int i = 0; i < 4; ++i)
        #pragma unroll
        for (int j = 0; j < 4; ++j)
            acc[i][j] = (f32x4_t){0.f, 0.f, 0.f, 0.f};

    for (int k0 = 0; k0 < 512; k0 += 32) {
        // stage A-tile [128][32] and B-tile [128][32] (f32 -> bf16)
        #pragma unroll
        for (int p = 0; p < 4; ++p) {
            int ch = tid + p * 256;          // 0..1023
            int r  = ch >> 3;                // 0..127
            int c  = ch & 7;                 // 0..7 (4-float chunk)
            float4 va = *(const float4*)(x    + (size_t)(m0 + r) * 512 + k0 + c * 4);
            float4 vb = *(const float4*)(W_in + (size_t)(n0 + r) * 512 + k0 + c * 4);
            ushort4 ha, hb;
            ha.x = f2bf(va.x); ha.y = f2bf(va.y); ha.z = f2bf(va.z); ha.w = f2bf(va.w);
            hb.x = f2bf(vb.x); hb.y = f2bf(vb.y); hb.z = f2bf(vb.z); hb.w = f2bf(vb.w);
            *(ushort4*)(&As[r * 32 + c * 4]) = ha;   // ds_write_b64
            *(ushort4*)(&Bs[r * 32 + c * 4]) = hb;
        }
        __syncthreads();

        bf16x8 af[4], bfr[4];
        #pragma unroll
        for (int mi = 0; mi < 4; ++mi)
            af[mi] = *(const bf16x8*)(&As[(wr * 64 + mi * 16 + fr) * 32 + fq * 8]);
        #pragma unroll
        for (int ni = 0; ni < 4; ++ni)
            bfr[ni] = *(const bf16x8*)(&Bs[(wc * 64 + ni * 16 + fr) * 32 + fq * 8]);

        #pragma unroll
        for (int mi = 0; mi < 4; ++mi)
            #pragma unroll
            for (int ni = 0; ni < 4; ++ni)
                acc[mi][ni] = __builtin_amdgcn_mfma_f32_16x16x32_bf16(
                                  af[mi], bfr[ni], acc[mi][ni], 0, 0, 0);
        __syncthreads();
    }

    // Epilogue: relu, gate (sigmoid(W_gate)), reduce d (quad lanes), store merged_in.
    float gv[4];
    #pragma unroll
    for (int ni = 0; ni < 4; ++ni) {
        int n = n0 + wc * 64 + ni * 16 + fr;
        gv[ni] = 1.f / (1.f + __expf(-W_gate[n]));
    }
    #pragma unroll
    for (int mi = 0; mi < 4; ++mi) {
        #pragma unroll
        for (int ni = 0; ni < 4; ++ni) {
            int n = n0 + wc * 64 + ni * 16 + fr;   // n = l*4 + d, d = lane&3
            int l = n >> 2;
            #pragma unroll
            for (int j = 0; j < 4; ++j) {
                float v = acc[mi][ni][j];
                float r = fmaxf(v, 0.f) * gv[ni];
                r += __shfl_xor(r, 1);             // sum over d within quad
                r += __shfl_xor(r, 2);
                if ((lane & 3) == 0) {
                    int row = m0 + wr * 64 + mi * 16 + fq * 4 + j;
                    merged[(size_t)row * 128 + l] = r;
                }
            }
        }
    }
}

// ---------------------------------------------------------------------------
// Phase 2: sequential scan over T=512. One block per batch (256 blocks),
// 512 threads: thread = (l,d) pair, owns W_liquid[l,d,0:128] in registers.
// State s[128] in LDS; layernorm via wave shfl reduce + per-wave LDS partials.
// ---------------------------------------------------------------------------
__global__ __launch_bounds__(512, 2)
void scan_kernel(const float* __restrict__ merged, const float* __restrict__ W_liq,
                 const float* __restrict__ W_gate, const float* __restrict__ b_liq,
                 const float* __restrict__ W_out, const float* __restrict__ b_out,
                 const float* __restrict__ ln_w, const float* __restrict__ ln_b,
                 const float* __restrict__ leaky, float* __restrict__ out)
{
    __shared__ float s[128];
    __shared__ float red[16];

    const int tid = threadIdx.x;   // = n = l*4+d
    const int b   = blockIdx.x;
    const int l   = tid >> 2;
    const int wid = tid >> 6;

    // W_liquid row for this (l,d) in registers: 128 f32 = 32 float4
    float4 w4[32];
    const float4* wl4 = (const float4*)(W_liq + (size_t)tid * 128);
    #pragma unroll
    for (int i = 0; i < 32; ++i) w4[i] = wl4[i];

    const float g     = 1.f / (1.f + __expf(-W_gate[tid]));
    const float bl    = b_liq[l];
    const float lw    = ln_w[l];
    const float lb    = ln_b[l];
    const float alpha = 1.f / (1.f + __expf(-leaky[0]));
    const float oma   = 1.f - alpha;

    if (tid < 128) s[tid] = 0.f;
    __syncthreads();

    const float* mi_ptr = merged + (size_t)b * (512 * 128);
    float mi_cur = mi_ptr[l];   // t = 0

    for (int t = 0; t < 512; ++t) {
        float mi_nxt = 0.f;
        if (t < 511) mi_nxt = mi_ptr[(t + 1) * 128 + l];   // prefetch next step

        // rec dot: acc = W_liquid[l,d,:] . state
        const float4* s4 = (const float4*)s;
        float acc = 0.f;
        #pragma unroll
        for (int i = 0; i < 32; ++i) {
            float4 sv = s4[i];                 // broadcast ds_read_b128
            acc = fmaf(w4[i].x, sv.x, acc);
            acc = fmaf(w4[i].y, sv.y, acc);
            acc = fmaf(w4[i].z, sv.z, acc);
            acc = fmaf(w4[i].w, sv.w, acc);
        }
        float s_old = s[l];

        float r = fmaxf(acc, 0.f) * g;
        r += __shfl_xor(r, 1);                 // sum over d (quad)
        r += __shfl_xor(r, 2);

        float li = mi_cur + r + bl;            // identical across the quad

        // layernorm reductions over the 128 l's
        float v1 = li, v2 = li * li;
        #pragma unroll
        for (int off = 4; off <= 32; off <<= 1) {
            v1 += __shfl_xor(v1, off);
            v2 += __shfl_xor(v2, off);
        }
        if ((tid & 63) == 0) { red[wid] = v1; red[8 + wid] = v2; }
        __syncthreads();
        float S1 = 0.f, S2 = 0.f;
        #pragma unroll
        for (int i = 0; i < 8; ++i) { S1 += red[i]; S2 += red[8 + i]; }

        float mean = S1 * (1.f / 128.f);
        float var  = S2 * (1.f / 128.f) - mean * mean;
        float rstd = rsqrtf(var + 1e-5f);
        float xn   = (li - mean) * rstd * lw + lb;

        // tanh(x) = 1 - 2/(1+e^{2x}) ; saturates correctly at +-inf
        float e  = __expf(2.f * xn);
        float th = 1.f - 2.f * __builtin_amdgcn_rcpf(e + 1.f);

        float ns = oma * s_old + alpha * th;
        if ((tid & 3) == 0) s[l] = ns;
        __syncthreads();

        mi_cur = mi_nxt;
    }

    // out[b, o] = state . W_out[o,:] + b_out[o]
    if (tid < 2) {
        float accO = b_out[tid];
        #pragma unroll
        for (int h = 0; h < 128; ++h)
            accO = fmaf(s[h], W_out[tid * 128 + h], accO);
        out[b * 2 + tid] = accO;
    }
}

extern "C" void kernel_launch(void* const* d_in, const int* in_sizes, int n_in,
                              void* d_out, int out_size, void* d_ws, size_t ws_size,
                              hipStream_t stream)
{
    const float* x      = (const float*)d_in[0];
    const float* W_in   = (const float*)d_in[1];
    const float* W_liq  = (const float*)d_in[2];
    const float* W_gate = (const float*)d_in[3];
    const float* b_liq  = (const float*)d_in[4];
    const float* W_out  = (const float*)d_in[5];
    const float* b_out  = (const float*)d_in[6];
    const float* ln_w   = (const float*)d_in[7];
    const float* ln_b   = (const float*)d_in[8];
    const float* leaky  = (const float*)d_in[9];
    float* out    = (float*)d_out;
    float* merged = (float*)d_ws;    // 131072 x 128 f32 = 64 MiB scratch

    // Phase 1: batched input-branch GEMM (grid: 4 n-blocks fastest for L2/L3
    // temporal locality on the shared A rows, 1024 m-blocks).
    gemm_in_kernel<<<dim3(4, 1024), 256, 0, stream>>>(x, W_in, W_gate, merged);

    // Phase 2: recurrent scan, one block per batch.
    scan_kernel<<<256, 512, 0, stream>>>(merged, W_liq, W_gate, b_liq,
                                         W_out, b_out, ln_w, ln_b, leaky, out);
}

// Round 2
// 690.486 us; speedup vs baseline: 1.1479x; 1.1479x over previous
//
#include <hip/hip_runtime.h>
#include <hip/hip_bf16.h>
#include <stdint.h>

// Problem dims (fixed): B=256, T=512, I=512, L=128, D=4, O=2
// GEMM: M = B*T = 131072, N = L*D = 512, K = I = 512

typedef __bf16 bf16x8 __attribute__((ext_vector_type(8)));
typedef float f32x4_t __attribute__((ext_vector_type(4)));

__device__ inline unsigned short f2bf(float f) {
    union { float f; unsigned u; } v; v.f = f;
    unsigned r = v.u + 0x7fffu + ((v.u >> 16) & 1u);   // round-to-nearest-even
    return (unsigned short)(r >> 16);
}

// ---------------------------------------------------------------------------
// Phase 1: merged_in[m][l] = sum_d gate[l*4+d] * relu( sum_k x[m][k]*W_in[l*4+d][k] )
// bf16 MFMA GEMM, 128x128 tile, BK=32 (unchanged from round 1).
// ---------------------------------------------------------------------------
__global__ __launch_bounds__(256, 2)
void gemm_in_kernel(const float* __restrict__ x, const float* __restrict__ W_in,
                    const float* __restrict__ W_gate, float* __restrict__ merged)
{
    __shared__ unsigned short As[128 * 32];
    __shared__ unsigned short Bs[128 * 32];

    const int tid = threadIdx.x;
    const int m0 = blockIdx.y * 128;
    const int n0 = blockIdx.x * 128;
    const int lane = tid & 63;
    const int wid  = tid >> 6;
    const int wr = wid >> 1, wc = wid & 1;
    const int fr = lane & 15, fq = lane >> 4;

    f32x4_t acc[4][4];
    #pragma unroll
    for (int i = 0; i < 4; ++i)
        #pragma unroll
        for (int j = 0; j < 4; ++j)
            acc[i][j] = (f32x4_t){0.f, 0.f, 0.f, 0.f};

    for (int k0 = 0; k0 < 512; k0 += 32) {
        #pragma unroll
        for (int p = 0; p < 4; ++p) {
            int ch = tid + p * 256;
            int r  = ch >> 3;
            int c  = ch & 7;
            float4 va = *(const float4*)(x    + (size_t)(m0 + r) * 512 + k0 + c * 4);
            float4 vb = *(const float4*)(W_in + (size_t)(n0 + r) * 512 + k0 + c * 4);
            ushort4 ha, hb;
            ha.x = f2bf(va.x); ha.y = f2bf(va.y); ha.z = f2bf(va.z); ha.w = f2bf(va.w);
            hb.x = f2bf(vb.x); hb.y = f2bf(vb.y); hb.z = f2bf(vb.z); hb.w = f2bf(vb.w);
            *(ushort4*)(&As[r * 32 + c * 4]) = ha;
            *(ushort4*)(&Bs[r * 32 + c * 4]) = hb;
        }
        __syncthreads();

        bf16x8 af[4], bfr[4];
        #pragma unroll
        for (int mi = 0; mi < 4; ++mi)
            af[mi] = *(const bf16x8*)(&As[(wr * 64 + mi * 16 + fr) * 32 + fq * 8]);
        #pragma unroll
        for (int ni = 0; ni < 4; ++ni)
            bfr[ni] = *(const bf16x8*)(&Bs[(wc * 64 + ni * 16 + fr) * 32 + fq * 8]);

        #pragma unroll
        for (int mi = 0; mi < 4; ++mi)
            #pragma unroll
            for (int ni = 0; ni < 4; ++ni)
                acc[mi][ni] = __builtin_amdgcn_mfma_f32_16x16x32_bf16(
                                  af[mi], bfr[ni], acc[mi][ni], 0, 0, 0);
        __syncthreads();
    }

    float gv[4];
    #pragma unroll
    for (int ni = 0; ni < 4; ++ni) {
        int n = n0 + wc * 64 + ni * 16 + fr;
        gv[ni] = 1.f / (1.f + __expf(-W_gate[n]));
    }
    #pragma unroll
    for (int mi = 0; mi < 4; ++mi) {
        #pragma unroll
        for (int ni = 0; ni < 4; ++ni) {
            int n = n0 + wc * 64 + ni * 16 + fr;
            int l = n >> 2;
            #pragma unroll
            for (int j = 0; j < 4; ++j) {
                float v = acc[mi][ni][j];
                float r = fmaxf(v, 0.f) * gv[ni];
                r += __shfl_xor(r, 1);
                r += __shfl_xor(r, 2);
                if ((lane & 3) == 0) {
                    int row = m0 + wr * 64 + mi * 16 + fq * 4 + j;
                    merged[(size_t)row * 128 + l] = r;
                }
            }
        }
    }
}

// ---------------------------------------------------------------------------
// Phase 2: recurrent scan, MFMA-based. One block per batch (256 blocks = 1/CU),
// 512 threads = 8 waves. Wave w owns rows n in [w*64, w*64+64) of W_liquid,
// pre-converted to bf16 and pinned in registers (16 fragments = 64 VGPR/lane).
// Per step: state (bf16, LDS[128]) is broadcast into ALL 16 B-fragment columns
// -> every lane's accumulator holds valid rec values, replicated 16x across
// lane&15. Lane (fq=lane>>4), tile mi owns l = w*16 + mi*4 + fq; its 4 acc
// regs are exactly d=0..3, so the gate-reduce is intra-lane.
// ---------------------------------------------------------------------------
__global__ __launch_bounds__(512, 2)
void scan_kernel(const float* __restrict__ merged, const float* __restrict__ W_liq,
                 const float* __restrict__ W_gate, const float* __restrict__ b_liq,
                 const float* __restrict__ W_out, const float* __restrict__ b_out,
                 const float* __restrict__ ln_w, const float* __restrict__ ln_b,
                 const float* __restrict__ leaky, float* __restrict__ out)
{
    __shared__ __align__(16) unsigned short s_bf[128];   // state, bf16
    __shared__ __align__(16) float red[16];              // per-wave LN partials
    __shared__ float s_final[128];

    const int tid  = threadIdx.x;
    const int b    = blockIdx.x;
    const int lane = tid & 63;
    const int w    = tid >> 6;        // wave 0..7
    const int fr   = lane & 15;       // replica/column id
    const int fq   = lane >> 4;       // 0..3

    // ---- one-time preloads ----
    // W_liquid fragments: tile mi covers rows w*64+mi*16+fr, chunk kk covers
    // k = kk*32 + fq*8 .. +8. Same (row,k)->lane mapping as the GEMM (any
    // common k-permutation cancels between A and B fragments).
    bf16x8 wfrag[4][4];
    #pragma unroll
    for (int mi = 0; mi < 4; ++mi) {
        const float* wrow = W_liq + (size_t)(w * 64 + mi * 16 + fr) * 128;
        #pragma unroll
        for (int kk = 0; kk < 4; ++kk) {
            float4 f0 = *(const float4*)(wrow + kk * 32 + fq * 8);
            float4 f1 = *(const float4*)(wrow + kk * 32 + fq * 8 + 4);
            union { unsigned short u[8]; bf16x8 v; } cv;
            cv.u[0] = f2bf(f0.x); cv.u[1] = f2bf(f0.y);
            cv.u[2] = f2bf(f0.z); cv.u[3] = f2bf(f0.w);
            cv.u[4] = f2bf(f1.x); cv.u[5] = f2bf(f1.y);
            cv.u[6] = f2bf(f1.z); cv.u[7] = f2bf(f1.w);
            wfrag[mi][kk] = cv.v;
        }
    }

    // Per-(lane,mi) liquid unit l and its constants.
    int   l_mi[4];
    float gv[4][4], blv[4], lwv[4], lbv[4];
    size_t midx[4];
    #pragma unroll
    for (int mi = 0; mi < 4; ++mi) {
        int l = w * 16 + mi * 4 + fq;
        l_mi[mi] = l;
        #pragma unroll
        for (int r = 0; r < 4; ++r)
            gv[mi][r] = 1.f / (1.f + __expf(-W_gate[l * 4 + r]));
        blv[mi] = b_liq[l];
        lwv[mi] = ln_w[l];
        lbv[mi] = ln_b[l];
        midx[mi] = (size_t)b * 65536 + l;
    }
    const float alpha = 1.f / (1.f + __expf(-leaky[0]));
    const float oma   = 1.f - alpha;

    float s_reg[4] = {0.f, 0.f, 0.f, 0.f};   // state for owned l's (replicated)
    float cur[4];
    #pragma unroll
    for (int mi = 0; mi < 4; ++mi) cur[mi] = merged[midx[mi]];   // t=0

    if (tid < 64) ((unsigned*)s_bf)[tid] = 0u;   // state_0 = 0
    __syncthreads();

    const f32x4_t z = {0.f, 0.f, 0.f, 0.f};

    for (int t = 0; t < 512; ++t) {
        // B fragments: broadcast state into all 16 columns.
        bf16x8 bfr[4];
        #pragma unroll
        for (int kk = 0; kk < 4; ++kk)
            bfr[kk] = *(const bf16x8*)(&s_bf[kk * 32 + fq * 8]);

        // prefetch merged_in for t+1
        float nxt[4] = {0.f, 0.f, 0.f, 0.f};
        if (t < 511) {
            #pragma unroll
            for (int mi = 0; mi < 4; ++mi)
                nxt[mi] = merged[midx[mi] + (size_t)(t + 1) * 128];
        }

        // rec = W_liq . state  (16 MFMA, fresh accumulate via C=0)
        f32x4_t acc[4];
        #pragma unroll
        for (int mi = 0; mi < 4; ++mi)
            acc[mi] = __builtin_amdgcn_mfma_f32_16x16x32_bf16(wfrag[mi][0], bfr[0], z, 0, 0, 0);
        #pragma unroll
        for (int kk = 1; kk < 4; ++kk)
            #pragma unroll
            for (int mi = 0; mi < 4; ++mi)
                acc[mi] = __builtin_amdgcn_mfma_f32_16x16x32_bf16(wfrag[mi][kk], bfr[kk], acc[mi], 0, 0, 0);

        // epilogue: relu, gate-dot over d (intra-lane regs), li, LN moments
        float li[4], v1 = 0.f, v2 = 0.f;
        #pragma unroll
        for (int mi = 0; mi < 4; ++mi) {
            float mr = gv[mi][0] * fmaxf(acc[mi][0], 0.f);
            mr = fmaf(gv[mi][1], fmaxf(acc[mi][1], 0.f), mr);
            mr = fmaf(gv[mi][2], fmaxf(acc[mi][2], 0.f), mr);
            mr = fmaf(gv[mi][3], fmaxf(acc[mi][3], 0.f), mr);
            li[mi] = cur[mi] + mr + blv[mi];
            v1 += li[mi];
            v2 = fmaf(li[mi], li[mi], v2);
        }
        // sum over fq groups (xor 16, 32); replicas along fr stay consistent
        v1 += __shfl_xor(v1, 16);  v2 += __shfl_xor(v2, 16);
        v1 += __shfl_xor(v1, 32);  v2 += __shfl_xor(v2, 32);
        if (lane == 0) { red[w] = v1; red[8 + w] = v2; }
        __syncthreads();

        float4 ra = *(const float4*)&red[0], rb = *(const float4*)&red[4];
        float4 rc = *(const float4*)&red[8], rd = *(const float4*)&red[12];
        float S1 = ((ra.x + ra.y) + (ra.z + ra.w)) + ((rb.x + rb.y) + (rb.z + rb.w));
        float S2 = ((rc.x + rc.y) + (rc.z + rc.w)) + ((rd.x + rd.y) + (rd.z + rd.w));
        float mean = S1 * (1.f / 128.f);
        float var  = fmaf(-mean, mean, S2 * (1.f / 128.f));
        float rstd = rsqrtf(var + 1e-5f);

        #pragma unroll
        for (int mi = 0; mi < 4; ++mi) {
            float t1 = rstd * lwv[mi];
            float xn = fmaf(li[mi], t1, fmaf(-mean, t1, lbv[mi]));
            float e  = __expf(2.f * xn);
            float th = fmaf(-2.f, __builtin_amdgcn_rcpf(e + 1.f), 1.f);
            float ns = fmaf(oma, s_reg[mi], alpha * th);
            s_reg[mi] = ns;
            cur[mi]   = nxt[mi];
        }
        if (fr == 0) {
            #pragma unroll
            for (int mi = 0; mi < 4; ++mi)
                s_bf[l_mi[mi]] = f2bf(s_reg[mi]);
        }
        __syncthreads();
    }

    // final state -> LDS f32, then tiny output matvec
    if (fr == 0) {
        #pragma unroll
        for (int mi = 0; mi < 4; ++mi) s_final[l_mi[mi]] = s_reg[mi];
    }
    __syncthreads();
    if (tid < 2) {
        float accO = b_out[tid];
        #pragma unroll
        for (int h = 0; h < 128; ++h)
            accO = fmaf(s_final[h], W_out[tid * 128 + h], accO);
        out[b * 2 + tid] = accO;
    }
}

extern "C" void kernel_launch(void* const* d_in, const int* in_sizes, int n_in,
                              void* d_out, int out_size, void* d_ws, size_t ws_size,
                              hipStream_t stream)
{
    const float* x      = (const float*)d_in[0];
    const float* W_in   = (const float*)d_in[1];
    const float* W_liq  = (const float*)d_in[2];
    const float* W_gate = (const float*)d_in[3];
    const float* b_liq  = (const float*)d_in[4];
    const float* W_out  = (const float*)d_in[5];
    const float* b_out  = (const float*)d_in[6];
    const float* ln_w   = (const float*)d_in[7];
    const float* ln_b   = (const float*)d_in[8];
    const float* leaky  = (const float*)d_in[9];
    float* out    = (float*)d_out;
    float* merged = (float*)d_ws;    // 131072 x 128 f32 = 64 MiB scratch

    gemm_in_kernel<<<dim3(4, 1024), 256, 0, stream>>>(x, W_in, W_gate, merged);
    scan_kernel<<<256, 512, 0, stream>>>(merged, W_liq, W_gate, b_liq,
                                         W_out, b_out, ln_w, ln_b, leaky, out);
}